// Round 7
// baseline (316.040 us; speedup 1.0000x reference)
//
#include <hip/hip_runtime.h>

#define B_ 256
#define T_ 2048
#define F_ 20
#define NT (B_*T_)
#define CH 16
#define NCH (T_/CH)   // 128 chunks

typedef __bf16 bf16x8 __attribute__((ext_vector_type(8)));
typedef float  f32x4  __attribute__((ext_vector_type(4)));

__device__ __forceinline__ float ex2(float x){ return __builtin_amdgcn_exp2f(x); }
__device__ __forceinline__ float rcpf_(float x){ return __builtin_amdgcn_rcpf(x); }
__device__ __forceinline__ void setprio(int p){
  if (p == 3) asm volatile("s_setprio 3");
  else if (p == 2) asm volatile("s_setprio 2");
  else if (p == 1) asm volatile("s_setprio 1");
}

// 20*log2(e), 2*log2(e), log2(e), ln2/20
#define K10F 28.853900817779268f
#define INVK 0.034657359027997264f
#define K1F   2.8853900817779268f
#define LOG2E 1.4426950408889634f

__device__ __forceinline__ float hside(float x){ return 1.0f - rcpf_(ex2(K10F*x) + 1.0f); }
__device__ __forceinline__ float tanh_f(float z){ return 1.0f - 2.0f*rcpf_(ex2(K1F*z) + 1.0f); }
__device__ __forceinline__ float sigmoid_f(float z){ return rcpf_(1.0f + ex2(-LOG2E*z)); }

// ws float layout (b-major, rho = b*T + t):
// wuT [0,NT) | wdT [NT,2NT) | pk4 [2NT,6NT) float4/row {A,B,KP,_} | pT [6NT,7NT)

struct ScanS {
  float2 ppL[2][CH][32];   // {K*pet, K*(p-pet)}       loader -> W0
  float  dkR[2][CH][32];   // dK = K*d1                W0 -> W1 (lag1)
  float  bsR[4][CH][32];   // BASE = K*(p-et1)         W0 -> W2 (lag2)
  float  wuR[2][CH][32];   // Wu'                      W0 -> writer (lag1)
  float2 rhR[2][CH][32];   // {RP, HRP}                W1 -> W2 (lag1)
  float2 qbR[2][CH][32];   // {QV, B2}                 W2 -> W3 (lag1)
  float  wdR[2][CH][32];   // WD'                      W3 -> writer (lag1)
};
struct MlpS {
  __bf16 w1f[16*32*8];
  __bf16 w2f[32*64*8];
  float  b1s[256];
  float  b2s[64];
  float  w3s[512];
  float  b3s[8];
  __bf16 hbuf[8][1152];
};
union SMu { ScanS s; MlpS m; };

// blocks 0..7: pipelined scan, 32 batches each (waves: 0=wu,1=rp/hrp,2=wl,3=wd/hq,4=loader,5=writer,6-7=idle)
// blocks 8..4103: MFMA MLP, 128 b-major rows each
__global__ __launch_bounds__(512) void fused_kernel(const float* __restrict__ in,
    const float* __restrict__ w1, const float* __restrict__ b1,
    const float* __restrict__ w2, const float* __restrict__ b2,
    const float* __restrict__ w3, const float* __restrict__ b3,
    float* __restrict__ ws){
  __shared__ SMu smu;

  if (blockIdx.x < 8) {
    ScanS& S = smu.s;
    float* wuT = ws;
    float* wdT = ws + (size_t)NT;
    float* pT  = ws + 6*(size_t)NT;
    int tid  = threadIdx.x;
    int wv   = tid >> 6;
    int lane = tid & 31;
    bool act = (tid & 63) < 32;
    int bmy  = blockIdx.x*32 + lane;
    const float* inb = in + (size_t)bmy*T_*F_;

    setprio(3);                              // scan waves win issue arbitration vs MLP

    float Wu = 0.0f, WL = 0.0f, WD = 0.0f;   // K-scaled state
    float2 v[CH];                            // loader prefetch regs

    if (wv == 4 && act){
      #pragma unroll
      for (int s = 0; s < CH; ++s){
        float4 r4 = *(const float4*)(inb + (size_t)s*F_);
        v[s] = make_float2(r4.x, r4.z);      // pet, p
      }
      #pragma unroll
      for (int s = 0; s < CH; ++s)
        S.ppL[0][s][lane] = make_float2(K10F*v[s].x, K10F*(v[s].y - v[s].x));
      float* pdst = &pT[(size_t)bmy*T_];
      #pragma unroll
      for (int g = 0; g < 4; ++g)
        *(float4*)(pdst + g*4) = make_float4(v[g*4].y, v[g*4+1].y, v[g*4+2].y, v[g*4+3].y);
      #pragma unroll
      for (int s = 0; s < CH; ++s){
        float4 r4 = *(const float4*)(inb + (size_t)(CH + s)*F_);
        v[s] = make_float2(r4.x, r4.z);
      }
    }
    __syncthreads();

    for (int it = 0; it < NCH + 4; ++it){
      if (wv == 0){                               // wu chain, chunk c = it
        int c = it;
        if (c < NCH && act){
          float2 pe[CH];
          #pragma unroll
          for (int s = 0; s < CH; ++s) pe[s] = S.ppL[c&1][s][lane];
          float dk_[CH], bs_[CH], wu_[CH];
          #pragma unroll
          for (int s = 0; s < CH; ++s){
            float t1 = Wu - pe[s].x;
            float r  = rcpf_(ex2(t1) + 1.0f);
            float dK = -t1*r;
            float BS = pe[s].y + dK;
            Wu += BS;
            dk_[s] = dK; bs_[s] = BS; wu_[s] = Wu;
          }
          #pragma unroll
          for (int s = 0; s < CH; ++s) S.dkR[c&1][s][lane] = dk_[s];
          #pragma unroll
          for (int s = 0; s < CH; ++s) S.bsR[c&3][s][lane] = bs_[s];
          #pragma unroll
          for (int s = 0; s < CH; ++s) S.wuR[c&1][s][lane] = wu_[s];
        }
      } else if (wv == 1){                        // RP + HRP (stateless), c = it-1
        int c = it - 1;
        if (c >= 0 && c < NCH && act){
          float dk_[CH];
          #pragma unroll
          for (int s = 0; s < CH; ++s) dk_[s] = S.dkR[c&1][s][lane];
          float2 rh_[CH];
          #pragma unroll
          for (int s = 0; s < CH; ++s){
            float r1  = rcpf_(ex2(dk_[s]) + 1.0f);
            float RP  = fmaf(-dk_[s], r1, dk_[s]);        // = K*rp
            float HRP = 1.0f - rcpf_(ex2(RP) + 1.0f);     // = h(rp)
            rh_[s] = make_float2(RP, HRP);
          }
          #pragma unroll
          for (int s = 0; s < CH; ++s) S.rhR[c&1][s][lane] = rh_[s];
        }
      } else if (wv == 2){                        // wl chain, c = it-2
        int c = it - 2;
        if (c >= 0 && c < NCH && act){
          float2 rh_[CH]; float bs_[CH];
          #pragma unroll
          for (int s = 0; s < CH; ++s) rh_[s] = S.rhR[c&1][s][lane];
          #pragma unroll
          for (int s = 0; s < CH; ++s) bs_[s] = S.bsR[c&3][s][lane];
          float2 qb_[CH];
          #pragma unroll
          for (int s = 0; s < CH; ++s){
            float D2   = rh_[s].x - WL;
            float r    = rcpf_(ex2(D2) + 1.0f);
            float et22 = fmaf(D2, r, WL);
            float WLB  = WL + bs_[s];
            float ET2  = rh_[s].y * et22;
            WL = fmaf(-rh_[s].y, et22, WLB);
            qb_[s] = make_float2(rh_[s].x - ET2, bs_[s] - ET2);  // QV, B2
          }
          #pragma unroll
          for (int s = 0; s < CH; ++s) S.qbR[c&1][s][lane] = qb_[s];
        }
      } else if (wv == 3){                        // wd chain + HQ, c = it-3
        int c = it - 3;
        if (c >= 0 && c < NCH && act){
          float2 qb_[CH];
          #pragma unroll
          for (int s = 0; s < CH; ++s) qb_[s] = S.qbR[c&1][s][lane];
          float wd_[CH];
          #pragma unroll
          for (int s = 0; s < CH; ++s){
            float hqv  = 1.0f - rcpf_(ex2(qb_[s].x) + 1.0f); // stateless, off-chain
            float D3   = qb_[s].x - WD;
            float r    = rcpf_(ex2(D3) + 1.0f);
            float et33 = fmaf(D3, r, WD);
            float WDB  = WD + qb_[s].y;
            WD = fmaf(-hqv, et33, WDB);
            wd_[s] = WD;
          }
          #pragma unroll
          for (int s = 0; s < CH; ++s) S.wdR[c&1][s][lane] = wd_[s];
        }
      } else if (wv == 4){                        // loader: publish it+1, issue it+2
        int n = it + 1;
        if (n < NCH && act){
          float2 w[CH];
          #pragma unroll
          for (int s = 0; s < CH; ++s) w[s] = v[s];
          #pragma unroll
          for (int s = 0; s < CH; ++s)
            S.ppL[n&1][s][lane] = make_float2(K10F*w[s].x, K10F*(w[s].y - w[s].x));
          float* pdst = &pT[(size_t)bmy*T_ + n*CH];
          #pragma unroll
          for (int g = 0; g < 4; ++g)
            *(float4*)(pdst + g*4) = make_float4(w[g*4].y, w[g*4+1].y, w[g*4+2].y, w[g*4+3].y);
          int n2 = it + 2;
          if (n2 < NCH){
            #pragma unroll
            for (int s = 0; s < CH; ++s){
              float4 r4 = *(const float4*)(inb + (size_t)(n2*CH + s)*F_);
              v[s] = make_float2(r4.x, r4.z);
            }
          }
        }
      } else if (wv == 5){                        // writer: wu c=it-1, wd c=it-4 (b-major, per-lane contiguous)
        int c = it - 1;
        if (c >= 0 && c < NCH && act){
          float wu_[CH];
          #pragma unroll
          for (int s = 0; s < CH; ++s) wu_[s] = S.wuR[c&1][s][lane] * INVK;
          float* dst = &wuT[(size_t)bmy*T_ + c*CH];
          #pragma unroll
          for (int g = 0; g < 4; ++g)
            *(float4*)(dst + g*4) = make_float4(wu_[g*4], wu_[g*4+1], wu_[g*4+2], wu_[g*4+3]);
        }
        int cd = it - 4;
        if (cd >= 0 && cd < NCH && act){
          float wd_[CH];
          #pragma unroll
          for (int s = 0; s < CH; ++s) wd_[s] = S.wdR[cd&1][s][lane] * INVK;
          float* dst = &wdT[(size_t)bmy*T_ + cd*CH];
          #pragma unroll
          for (int g = 0; g < 4; ++g)
            *(float4*)(dst + g*4) = make_float4(wd_[g*4], wd_[g*4+1], wd_[g*4+2], wd_[g*4+3]);
        }
      }
      __syncthreads();
    }
    return;
  }

  // ================== MFMA MLP path (b-major rows) ==================
  MlpS& M = smu.m;
  float* pk4 = ws + 2*(size_t)NT;
  int tid = threadIdx.x;

  for (int s = tid; s < 16*32*8; s += 512) M.w1f[s] = (__bf16)0.0f;
  __syncthreads();
  for (int idx = tid; idx < 15*256; idx += 512){   // w1: (k,n) k<15
    int k = idx >> 8, n = idx & 255;
    int ct = n >> 4;
    int l  = ((k>>3)*16) + (n & 15);
    int j  = k & 7;
    M.w1f[(ct*32 + l)*8 + j] = (__bf16)w1[idx];
  }
  for (int idx = tid; idx < 256*64; idx += 512){   // w2: (k,n)
    int k = idx >> 6, n = idx & 63;
    int kb = k >> 5;
    int lq = (k >> 3) & 3;
    int j  = k & 7;
    int ct = n >> 4;
    int l  = lq*16 + (n & 15);
    M.w2f[((kb*4 + ct)*64 + l)*8 + j] = (__bf16)w2[idx];
  }
  if (tid < 256) M.b1s[tid] = b1[tid];
  if (tid < 64)  M.b2s[tid] = b2[tid];
  if (tid < 512) M.w3s[tid] = w3[tid];
  if (tid < 8)   M.b3s[tid] = b3[tid];
  __syncthreads();

  int lane = tid & 63;
  int wv   = tid >> 6;
  int m    = lane & 15;
  int q    = lane >> 4;
  int r0   = (blockIdx.x - 8)*128 + wv*16;    // b-major rho

  int rho = r0 + m;
  const float* ap = in + (size_t)rho*F_ + 5;
  bf16x8 a1;
  #pragma unroll
  for (int j = 0; j < 8; ++j){
    int k = q*8 + j;
    float vv = (k < 15) ? ap[k] : 0.0f;
    a1[j] = (__bf16)vv;
  }

  __bf16* hb = M.hbuf[wv];
  f32x4 zero4 = {0.0f, 0.0f, 0.0f, 0.0f};
  bf16x8 zero8;
  #pragma unroll
  for (int j = 0; j < 8; ++j) zero8[j] = (__bf16)0.0f;

  f32x4 acc2[4] = {zero4, zero4, zero4, zero4};

  #pragma unroll
  for (int p = 0; p < 4; ++p){
    #pragma unroll
    for (int c4 = 0; c4 < 4; ++c4){
      int ct = p*4 + c4;
      bf16x8 bw = zero8;
      if (lane < 32) bw = *(const bf16x8*)&M.w1f[(ct*32 + lane)*8];
      f32x4 c1 = __builtin_amdgcn_mfma_f32_16x16x32_bf16(a1, bw, zero4, 0, 0, 0);
      int f = c4*16 + m;
      float bb = M.b1s[p*64 + f];
      #pragma unroll
      for (int i = 0; i < 4; ++i){
        float h = tanh_f(c1[i] + bb);
        hb[(q*4 + i)*72 + f] = (__bf16)h;
      }
    }
    #pragma unroll
    for (int kb = 0; kb < 2; ++kb){
      bf16x8 a2 = *(const bf16x8*)&hb[m*72 + q*8 + kb*32];
      #pragma unroll
      for (int ct = 0; ct < 4; ++ct){
        bf16x8 bw2 = *(const bf16x8*)&M.w2f[(((p*2 + kb)*4 + ct)*64 + lane)*8];
        acc2[ct] = __builtin_amdgcn_mfma_f32_16x16x32_bf16(a2, bw2, acc2[ct], 0, 0, 0);
      }
    }
  }

  #pragma unroll
  for (int ct = 0; ct < 4; ++ct){
    int f = ct*16 + m;
    float bb = M.b2s[f];
    #pragma unroll
    for (int i = 0; i < 4; ++i){
      float h = tanh_f(acc2[ct][i] + bb);
      hb[(q*4 + i)*72 + f] = (__bf16)h;
    }
  }

  float z0 = M.b3s[2*q], z1 = M.b3s[2*q + 1];
  #pragma unroll
  for (int kb3 = 0; kb3 < 8; ++kb3){
    bf16x8 hv8 = *(const bf16x8*)&hb[m*72 + kb3*8];
    #pragma unroll
    for (int j = 0; j < 8; ++j){
      float hv = (float)hv8[j];
      int k = kb3*8 + j;
      z0 = fmaf(hv, M.w3s[k*8 + 2*q],     z0);
      z1 = fmaf(hv, M.w3s[k*8 + 2*q + 1], z1);
    }
  }

  // reduce 8 params -> {A, B, KP} per row (saves epilogue traffic + ALU)
  float* hf = (float*)hb;                       // reuse per-wave LDS as float scratch
  hf[m*8 + 2*q]     = sigmoid_f(z0);
  hf[m*8 + 2*q + 1] = sigmoid_f(z1);
  // same-wave DS ordering; compiler inserts lgkmcnt wait before dependent reads
  if (q == 0){
    float P0=hf[m*8+0], P1=hf[m*8+1], P2=hf[m*8+2], P3=hf[m*8+3];
    float P4=hf[m*8+4], P5=hf[m*8+5], P6=hf[m*8+6], P7=hf[m*8+7];
    // reference arg swap: _runoff(wu, wd, wl, p, wum, wdm, wlm, b, c)
    float wum = fmaf(P0, 19.9f, 0.1f);
    float wlm = fmaf(P2, 30.0f, 60.0f);     // wdm param lands in wlm slot
    float wdm = fmaf(P1, 60.0f, 60.0f);     // wlm param lands in wdm slot
    float wt  = wum + wlm + wdm;
    float rw  = 1.0f / wt;
    float cc  = fmaf(P4, 0.19f, 0.01f);
    float bc  = fmaf(P3, 0.30f, 0.10f);
    float A   = cc*rw*rw;
    float Bc  = bc*rw*rw;
    float k1  = fmaf(P5, 0.69f, 0.01f);
    float k2  = fmaf(P6, 0.69f, 0.01f);
    float k3  = fmaf(P7, 0.89f, 0.01f);
    float KP  = k1 + 0.5f*k2*(1.0f-k1) + 0.25f*k3*(1.0f-k1)*(1.0f-k2);
    *(float4*)&pk4[(size_t)rho*4] = make_float4(A, Bc, KP, 0.0f);
  }
}

// flat b-major elementwise epilogue: everything coalesced, 6 FLOPs + 1 sigma
__global__ __launch_bounds__(256) void final_kernel(const float* __restrict__ ws,
                                                    float* __restrict__ out){
  int rho = blockIdx.x*256 + threadIdx.x;
  if (rho >= NT) return;
  const float* wuT = ws;
  const float* wdT = ws + (size_t)NT;
  const float* pk4 = ws + 2*(size_t)NT;
  const float* pT  = ws + 6*(size_t)NT;

  float p  = pT[rho];
  float wu = wuT[rho], wd = wdT[rho];
  float4 k4 = *(const float4*)&pk4[(size_t)rho*4];
  float ps = p - k4.x*wu*wu - k4.y*wd*wd;
  float runoff = hside(ps)*ps;
  out[rho] = k4.z * runoff;
}

extern "C" void kernel_launch(void* const* d_in, const int* in_sizes, int n_in,
                              void* d_out, int out_size, void* d_ws, size_t ws_size,
                              hipStream_t stream) {
  const float* in = (const float*)d_in[0];
  const float* w1 = (const float*)d_in[1];
  const float* b1 = (const float*)d_in[2];
  const float* w2 = (const float*)d_in[3];
  const float* b2 = (const float*)d_in[4];
  const float* w3 = (const float*)d_in[5];
  const float* b3 = (const float*)d_in[6];
  float* out = (float*)d_out;
  float* ws  = (float*)d_ws;

  fused_kernel<<<NT/128 + 8, 512, 0, stream>>>(in, w1, b1, w2, b2, w3, b3, ws);
  final_kernel<<<NT/256,     256, 0, stream>>>(ws, out);
}

// Round 8
// 218.580 us; speedup vs baseline: 1.4459x; 1.4459x over previous
//
#include <hip/hip_runtime.h>

#define B_ 256
#define T_ 2048
#define F_ 20
#define NT (B_*T_)
#define CH 16
#define NCH (T_/CH)   // 128 chunks

typedef __bf16 bf16x8 __attribute__((ext_vector_type(8)));
typedef float  f32x4  __attribute__((ext_vector_type(4)));

__device__ __forceinline__ float ex2(float x){ return __builtin_amdgcn_exp2f(x); }
__device__ __forceinline__ float rcpf_(float x){ return __builtin_amdgcn_rcpf(x); }

// 20*log2(e), 2*log2(e), log2(e)
#define K10F 28.853900817779268f
#define K1F   2.8853900817779268f
#define LOG2E 1.4426950408889634f

__device__ __forceinline__ float hside(float x){ return 1.0f - rcpf_(ex2(K10F*x) + 1.0f); }
__device__ __forceinline__ float tanh_f(float z){ return 1.0f - 2.0f*rcpf_(ex2(K1F*z) + 1.0f); }
__device__ __forceinline__ float sigmoid_f(float z){ return rcpf_(1.0f + ex2(-LOG2E*z)); }

// ws float layout (t-major r = t*256 + b):
// pp2 [0,2NT) float2{pet,p} | wuT [2NT,3NT) | wdT [3NT,4NT) | pk4 [4NT,8NT) float4{A,B,KP,_}

__global__ __launch_bounds__(256) void prep_kernel(const float* __restrict__ in,
                                                   float* __restrict__ ws){
  int r = blockIdx.x*256 + threadIdx.x;
  if (r >= NT) return;
  int b = r & (B_-1);
  int t = r >> 8;
  const float* src = in + ((size_t)b*T_ + t)*F_;
  ((float2*)ws)[r] = make_float2(src[0], src[2]);  // pet, p
}

// blocks 0..3: pipelined scan (64 batches each, 4 pipeline waves) — R3-verbatim + setprio
// blocks 4..4099: MFMA MLP (128 rows each) — R3-verbatim + pk4 epilogue
__global__ __launch_bounds__(512) void fused_kernel(const float* __restrict__ in,
    const float* __restrict__ w1, const float* __restrict__ b1,
    const float* __restrict__ w2, const float* __restrict__ b2,
    const float* __restrict__ w3, const float* __restrict__ b3,
    float* __restrict__ ws){
  extern __shared__ char sm[];
  float* pk4 = ws + 4*(size_t)NT;

  if (blockIdx.x < 4) {
    // ================== pipelined Xinanjiang scan ==================
    asm volatile("s_setprio 3");            // scan waves win issue arbitration vs MLP waves
    const float2* pp2 = (const float2*)ws;
    float* wuT = ws + 2*(size_t)NT;
    float* wdT = ws + 3*(size_t)NT;
    float*  d1L = (float*)sm;                  // [2][CH][64]   8 KB
    float*  bsQ = (float*)(sm + 8192);         // [4][CH][64]  16 KB
    float2* rhL = (float2*)(sm + 24576);       // [2][CH][64]  16 KB {rp,hrp}
    float2* qbL = (float2*)(sm + 40960);       // [2][CH][64]  16 KB {qv,b2}

    int tid = threadIdx.x;
    int wv = tid >> 6, lane = tid & 63;
    int boff = blockIdx.x * 64;

    float wu = 0.0f, wl = 0.0f, wd = 0.0f;
    float2 buf[2][8];

    if (wv == 0){
      #pragma unroll
      for (int g = 0; g < 2; ++g)
        #pragma unroll
        for (int i = 0; i < 8; ++i)
          buf[g][i] = pp2[(g*8 + i)*B_ + boff + lane];
    }

    for (int it = 0; it < NCH + 3; ++it){
      if (wv == 0){
        if (it < NCH){
          int c = it, par = c & 1;
          #pragma unroll
          for (int g = 0; g < 2; ++g){
            #pragma unroll
            for (int i = 0; i < 8; ++i){
              int s = g*8 + i;
              float pet = buf[g][i].x, p = buf[g][i].y;
              float d  = wu - pet;
              float r1 = rcpf_(ex2(K10F*d) + 1.0f);
              float d1 = -d*r1;                       // pet - et1
              float base = (p - pet) + d1;            // p - et1
              wu += base;
              wuT[(c*CH + s)*B_ + boff + lane] = wu;
              d1L[par*(CH*64) + s*64 + lane] = d1;
              bsQ[(c&3)*(CH*64) + s*64 + lane] = base;
            }
            int cn = (c + 1 < NCH) ? c + 1 : c;       // prefetch next chunk, same group
            #pragma unroll
            for (int i = 0; i < 8; ++i)
              buf[g][i] = pp2[(cn*CH + g*8 + i)*B_ + boff + lane];
          }
        }
      } else if (wv == 1){
        if (it >= 1 && it <= NCH){
          int c = it - 1, par = c & 1;
          #pragma unroll
          for (int s = 0; s < CH; ++s){
            float d1 = d1L[par*(CH*64) + s*64 + lane];
            float r2 = rcpf_(ex2(K10F*d1) + 1.0f);
            float rp = fmaf(-d1, r2, d1);             // h(d1)*d1
            float hrp = 1.0f - rcpf_(ex2(K10F*rp) + 1.0f);
            rhL[par*(CH*64) + s*64 + lane] = make_float2(rp, hrp);
          }
        }
      } else if (wv == 2){
        if (it >= 2 && it <= NCH + 1){
          int c = it - 2, par = c & 1;
          #pragma unroll
          for (int s = 0; s < CH; ++s){
            float2 rh  = rhL[par*(CH*64) + s*64 + lane];
            float base = bsQ[(c&3)*(CH*64) + s*64 + lane];
            float d2   = rh.x - wl;
            float r    = rcpf_(ex2(K10F*d2) + 1.0f);
            float et22 = fmaf(d2, r, wl);
            float et2  = rh.y * et22;
            float b2   = base - et2;
            wl += b2;
            qbL[par*(CH*64) + s*64 + lane] = make_float2(rh.x - et2, b2); // qv, b2
          }
        }
      } else if (wv == 3){
        if (it >= 3){
          int c = it - 3, par = c & 1;
          #pragma unroll
          for (int s = 0; s < CH; ++s){
            float2 qb  = qbL[par*(CH*64) + s*64 + lane];
            float hqv  = 1.0f - rcpf_(ex2(K10F*qb.x) + 1.0f);
            float d3   = qb.x - wd;
            float r    = rcpf_(ex2(K10F*d3) + 1.0f);
            float et33 = fmaf(d3, r, wd);
            float et3  = hqv * et33;
            wd += qb.y - et3;
            wdT[(c*CH + s)*B_ + boff + lane] = wd;
          }
        }
      }
      __syncthreads();
    }
    return;
  }

  // ================== MFMA MLP path (R3-verbatim) ==================
  __bf16* w1f  = (__bf16*)sm;                // 8192 B
  __bf16* w2f  = (__bf16*)(sm + 8192);       // 32768 B
  float*  b1s  = (float*)(sm + 40960);
  float*  b2s  = (float*)(sm + 41984);
  float*  w3s  = (float*)(sm + 42240);
  float*  b3s  = (float*)(sm + 44288);
  __bf16* hbufA= (__bf16*)(sm + 44320);      // 8 waves × 16×72 bf16

  int tid = threadIdx.x;

  for (int s = tid; s < 16*32*8; s += 512) w1f[s] = (__bf16)0.0f;
  __syncthreads();
  for (int idx = tid; idx < 15*256; idx += 512){   // w1: (k,n) k<15
    int k = idx >> 8, n = idx & 255;
    int ct = n >> 4;
    int l  = ((k>>3)*16) + (n & 15);
    int j  = k & 7;
    w1f[(ct*32 + l)*8 + j] = (__bf16)w1[idx];
  }
  for (int idx = tid; idx < 256*64; idx += 512){   // w2: (k,n)
    int k = idx >> 6, n = idx & 63;
    int kb = k >> 5;
    int lq = (k >> 3) & 3;
    int j  = k & 7;
    int ct = n >> 4;
    int l  = lq*16 + (n & 15);
    w2f[((kb*4 + ct)*64 + l)*8 + j] = (__bf16)w2[idx];
  }
  if (tid < 256) b1s[tid] = b1[tid];
  if (tid < 64)  b2s[tid] = b2[tid];
  if (tid < 512) w3s[tid] = w3[tid];
  if (tid < 8)   b3s[tid] = b3[tid];
  __syncthreads();

  int lane = tid & 63;
  int wv   = tid >> 6;
  int m    = lane & 15;
  int q    = lane >> 4;
  int r0   = (blockIdx.x - 4)*128 + wv*16;   // t-major r

  int rowA = r0 + m;
  int bA = rowA & (B_-1), tA = rowA >> 8;
  const float* ap = in + ((size_t)bA*T_ + tA)*F_ + 5;
  bf16x8 a1;
  #pragma unroll
  for (int j = 0; j < 8; ++j){
    int k = q*8 + j;
    float v = (k < 15) ? ap[k] : 0.0f;
    a1[j] = (__bf16)v;
  }

  __bf16* hb = hbufA + wv*1152;
  f32x4 zero4 = {0.0f, 0.0f, 0.0f, 0.0f};
  bf16x8 zero8;
  #pragma unroll
  for (int j = 0; j < 8; ++j) zero8[j] = (__bf16)0.0f;

  f32x4 acc2[4] = {zero4, zero4, zero4, zero4};

  #pragma unroll
  for (int p = 0; p < 4; ++p){
    #pragma unroll
    for (int c4 = 0; c4 < 4; ++c4){
      int ct = p*4 + c4;
      bf16x8 bw = zero8;
      if (lane < 32) bw = *(const bf16x8*)&w1f[(ct*32 + lane)*8];
      f32x4 c1 = __builtin_amdgcn_mfma_f32_16x16x32_bf16(a1, bw, zero4, 0, 0, 0);
      int f = c4*16 + m;
      float bb = b1s[p*64 + f];
      #pragma unroll
      for (int i = 0; i < 4; ++i){
        float h = tanh_f(c1[i] + bb);
        hb[(q*4 + i)*72 + f] = (__bf16)h;
      }
    }
    #pragma unroll
    for (int kb = 0; kb < 2; ++kb){
      bf16x8 a2 = *(const bf16x8*)&hb[m*72 + q*8 + kb*32];
      #pragma unroll
      for (int ct = 0; ct < 4; ++ct){
        bf16x8 bw2 = *(const bf16x8*)&w2f[(((p*2 + kb)*4 + ct)*64 + lane)*8];
        acc2[ct] = __builtin_amdgcn_mfma_f32_16x16x32_bf16(a2, bw2, acc2[ct], 0, 0, 0);
      }
    }
  }

  #pragma unroll
  for (int ct = 0; ct < 4; ++ct){
    int f = ct*16 + m;
    float bb = b2s[f];
    #pragma unroll
    for (int i = 0; i < 4; ++i){
      float h = tanh_f(acc2[ct][i] + bb);
      hb[(q*4 + i)*72 + f] = (__bf16)h;
    }
  }

  float z0 = b3s[2*q], z1 = b3s[2*q + 1];
  #pragma unroll
  for (int kb3 = 0; kb3 < 8; ++kb3){
    bf16x8 hv8 = *(const bf16x8*)&hb[m*72 + kb3*8];
    #pragma unroll
    for (int j = 0; j < 8; ++j){
      float hv = (float)hv8[j];
      int k = kb3*8 + j;
      z0 = fmaf(hv, w3s[k*8 + 2*q],     z0);
      z1 = fmaf(hv, w3s[k*8 + 2*q + 1], z1);
    }
  }

  // reduce 8 params -> {A, B, KP} per row (cuts final-kernel traffic 2.3x)
  float* hf = (float*)hb;                       // reuse per-wave LDS as float scratch
  hf[m*8 + 2*q]     = sigmoid_f(z0);
  hf[m*8 + 2*q + 1] = sigmoid_f(z1);
  // same-wave DS ordering; compiler inserts lgkmcnt wait before dependent reads
  if (q == 0){
    float P0=hf[m*8+0], P1=hf[m*8+1], P2=hf[m*8+2], P3=hf[m*8+3];
    float P4=hf[m*8+4], P5=hf[m*8+5], P6=hf[m*8+6], P7=hf[m*8+7];
    // reference arg swap: _runoff(wu, wd, wl, p, wum, wdm, wlm, b, c)
    float wum = fmaf(P0, 19.9f, 0.1f);
    float wlm = fmaf(P2, 30.0f, 60.0f);     // wdm param lands in wlm slot
    float wdm = fmaf(P1, 60.0f, 60.0f);     // wlm param lands in wdm slot
    float wt  = wum + wlm + wdm;
    float rw  = 1.0f / wt;
    float cc  = fmaf(P4, 0.19f, 0.01f);
    float bc  = fmaf(P3, 0.30f, 0.10f);
    float A   = cc*rw*rw;
    float Bc  = bc*rw*rw;
    float k1  = fmaf(P5, 0.69f, 0.01f);
    float k2  = fmaf(P6, 0.69f, 0.01f);
    float k3  = fmaf(P7, 0.89f, 0.01f);
    float KP  = k1 + 0.5f*k2*(1.0f-k1) + 0.25f*k3*(1.0f-k1)*(1.0f-k2);
    int rowO = r0 + m;
    *(float4*)&pk4[(size_t)rowO*4] = make_float4(A, Bc, KP, 0.0f);
  }
}

// 64t × 64b tile; coalesced reads of t-major arrays, LDS transpose, coalesced out-writes
__global__ __launch_bounds__(256) void final_kernel(const float* __restrict__ ws,
                                                    float* __restrict__ out){
  __shared__ float tile[64*65];
  int tb = blockIdx.x & 31;
  int bb = blockIdx.x >> 5;
  int t0 = tb*64, b0 = bb*64;
  int tid = threadIdx.x;
  const float2* pp2 = (const float2*)ws;
  const float* wuT  = ws + 2*(size_t)NT;
  const float* wdT  = ws + 3*(size_t)NT;
  const float* pk4  = ws + 4*(size_t)NT;

  #pragma unroll
  for (int k = 0; k < 16; ++k){
    int idx = k*256 + tid;
    int tl = idx >> 6, bl = idx & 63;
    int r = (t0 + tl)*B_ + b0 + bl;
    float p  = pp2[r].y;
    float wu = wuT[r], wd = wdT[r];
    float4 k4 = *(const float4*)&pk4[(size_t)r*4];
    float ps = p - k4.x*wu*wu - k4.y*wd*wd;
    float runoff = hside(ps)*ps;
    tile[bl*65 + tl] = k4.z * runoff;
  }
  __syncthreads();
  #pragma unroll
  for (int k = 0; k < 16; ++k){
    int idx = k*256 + tid;
    int tl2 = idx & 63, bl2 = idx >> 6;
    out[(size_t)(b0 + bl2)*T_ + t0 + tl2] = tile[bl2*65 + tl2];
  }
}

extern "C" void kernel_launch(void* const* d_in, const int* in_sizes, int n_in,
                              void* d_out, int out_size, void* d_ws, size_t ws_size,
                              hipStream_t stream) {
  const float* in = (const float*)d_in[0];
  const float* w1 = (const float*)d_in[1];
  const float* b1 = (const float*)d_in[2];
  const float* w2 = (const float*)d_in[3];
  const float* b2 = (const float*)d_in[4];
  const float* w3 = (const float*)d_in[5];
  const float* b3 = (const float*)d_in[6];
  float* out = (float*)d_out;
  float* ws  = (float*)d_ws;

  prep_kernel <<<NT/256,     256, 0,     stream>>>(in, ws);
  fused_kernel<<<NT/128 + 4, 512, 62752, stream>>>(in, w1, b1, w2, b2, w3, b3, ws);
  final_kernel<<<128,        256, 0,     stream>>>(ws, out);
}